// Round 3
// baseline (842.696 us; speedup 1.0000x reference)
//
#include <hip/hip_runtime.h>

#define N_NODES 100000
#define N_EDGES 1600000
// DIN=128, DH=128, DOUT=64
#define SCAN_BLOCKS 98        // ceil(100000/1024)
#define BUCKET_SHIFT 7
#define NB 782                // ceil(100000/128) buckets of 128 nodes

// ---------------- zero ----------------
__global__ __launch_bounds__(256) void k_zero(int* __restrict__ indeg, int* __restrict__ bcnt) {
    int i = blockIdx.x * 256 + threadIdx.x;
    if (i < N_NODES) indeg[i] = 0;
    if (i < NB) bcnt[i] = 0;
}

// ---------------- fused histogram: global indeg + LDS bucket hist ----------------
__global__ __launch_bounds__(256) void k_bhist(const int* __restrict__ dst, int* __restrict__ indeg,
                                               int* __restrict__ bcnt) {
    __shared__ int lh[NB];
    for (int i = threadIdx.x; i < NB; i += 256) lh[i] = 0;
    __syncthreads();
    int base = blockIdx.x * 2048 + threadIdx.x;
#pragma unroll
    for (int j = 0; j < 8; ++j) {
        int e = base + j * 256;
        if (e < N_EDGES) {
            int d = dst[e];
            atomicAdd(&indeg[d], 1);
            atomicAdd(&lh[d >> BUCKET_SHIFT], 1);
        }
    }
    __syncthreads();
    for (int i = threadIdx.x; i < NB; i += 256)
        if (lh[i]) atomicAdd(&bcnt[i], lh[i]);
}

__global__ __launch_bounds__(256) void k_dinv(const int* __restrict__ indeg, float* __restrict__ dinv) {
    int i = blockIdx.x * 256 + threadIdx.x;
    if (i < N_NODES) dinv[i] = rsqrtf(1.0f + (float)indeg[i]);  // +1 = self loop
}

// ---------------- exclusive scan (rowptr) ----------------
__global__ __launch_bounds__(256) void k_scan1(const int* __restrict__ indeg, int* __restrict__ rowptr,
                                               int* __restrict__ bsums) {
    __shared__ int sh[256];
    int t = threadIdx.x;
    int base = blockIdx.x * 1024 + t * 4;
    int v0 = (base + 0 < N_NODES) ? indeg[base + 0] : 0;
    int v1 = (base + 1 < N_NODES) ? indeg[base + 1] : 0;
    int v2 = (base + 2 < N_NODES) ? indeg[base + 2] : 0;
    int v3 = (base + 3 < N_NODES) ? indeg[base + 3] : 0;
    int s = v0 + v1 + v2 + v3;
    sh[t] = s;
    __syncthreads();
    for (int off = 1; off < 256; off <<= 1) {
        int u = (t >= off) ? sh[t - off] : 0;
        __syncthreads();
        sh[t] += u;
        __syncthreads();
    }
    int excl = sh[t] - s;
    if (t == 255) bsums[blockIdx.x] = sh[t];
    int o = excl;
    if (base + 0 < N_NODES) rowptr[base + 0] = o; o += v0;
    if (base + 1 < N_NODES) rowptr[base + 1] = o; o += v1;
    if (base + 2 < N_NODES) rowptr[base + 2] = o; o += v2;
    if (base + 3 < N_NODES) rowptr[base + 3] = o;
}

__global__ __launch_bounds__(128) void k_scan2(int* __restrict__ bsums) {
    __shared__ int sh[128];
    int t = threadIdx.x;
    int v = (t < SCAN_BLOCKS) ? bsums[t] : 0;
    sh[t] = v;
    __syncthreads();
    for (int off = 1; off < 128; off <<= 1) {
        int u = (t >= off) ? sh[t - off] : 0;
        __syncthreads();
        sh[t] += u;
        __syncthreads();
    }
    if (t < SCAN_BLOCKS) bsums[t] = sh[t] - v;
}

__global__ __launch_bounds__(256) void k_scan3(int* __restrict__ rowptr, const int* __restrict__ bsums) {
    int i = blockIdx.x * 256 + threadIdx.x;
    if (i < N_NODES) rowptr[i] += bsums[i >> 10];
    if (i == 0) rowptr[N_NODES] = N_EDGES;
}

// ---------------- bucket scan (1 block over NB counts) ----------------
__global__ __launch_bounds__(1024) void k_bscan(const int* __restrict__ bcnt, int* __restrict__ bbase,
                                                int* __restrict__ bcur) {
    __shared__ int sh[1024];
    int t = threadIdx.x;
    int v = (t < NB) ? bcnt[t] : 0;
    sh[t] = v;
    __syncthreads();
    for (int off = 1; off < 1024; off <<= 1) {
        int u = (t >= off) ? sh[t - off] : 0;
        __syncthreads();
        sh[t] += u;
        __syncthreads();
    }
    if (t < NB) {
        bbase[t] = sh[t] - v;
        bcur[t] = sh[t] - v;
    }
}

// ---------------- scatter edges into bucket-ordered ebuf ----------------
__global__ __launch_bounds__(256) void k_bscatter(const int* __restrict__ src, const int* __restrict__ dst,
                                                  int* __restrict__ bcur, int2* __restrict__ ebuf) {
    int e = blockIdx.x * 256 + threadIdx.x;
    if (e < N_EDGES) {
        int s = src[e], d = dst[e];
        int pos = atomicAdd(&bcur[d >> BUCKET_SHIFT], 1);
        ebuf[pos] = make_int2(s, d);
    }
}

// ---------------- per-bucket CSR fill (LDS cursors, local writes) ----------------
__global__ __launch_bounds__(256) void k_bfill(const int2* __restrict__ ebuf, const int* __restrict__ bbase,
                                               const int* __restrict__ bcnt, const int* __restrict__ rowptr,
                                               int* __restrict__ csr) {
    __shared__ int lcur[128];
    int b = blockIdx.x;
    int node0 = b << BUCKET_SHIFT;
    int t = threadIdx.x;
    if (t < 128) {
        int n = node0 + t;
        lcur[t] = (n < N_NODES) ? rowptr[n] : 0;
    }
    __syncthreads();
    int s0 = bbase[b], cnt = bcnt[b];
    for (int i = t; i < cnt; i += 256) {
        int2 e = ebuf[s0 + i];
        int p = atomicAdd(&lcur[e.y - node0], 1);
        csr[p] = e.x;
    }
}

// ---------------- GEMM1: hs = (x @ W1) * dinv[row] ----------------
__global__ __launch_bounds__(256) void k_gemm1(const float* __restrict__ x, const float* __restrict__ W1,
                                               const float* __restrict__ dinv, float* __restrict__ hs) {
    __shared__ float Wl[128 * 128];
    __shared__ float Xl[32 * 128];
    int t = threadIdx.x;
    int row0 = blockIdx.x * 32;
    {
        const float4* W4 = (const float4*)W1;
        float4* Wl4 = (float4*)Wl;
#pragma unroll
        for (int i = 0; i < 16; ++i) Wl4[t + i * 256] = W4[t + i * 256];
        const float4* x4 = (const float4*)(x + (long long)row0 * 128);
        float4* Xl4 = (float4*)Xl;
#pragma unroll
        for (int i = 0; i < 4; ++i) Xl4[t + i * 256] = x4[t + i * 256];
    }
    __syncthreads();
    int tc = t & 31;
    int tr = t >> 5;
    float acc[4][4] = {};
    for (int k = 0; k < 128; ++k) {
        float4 w = *(const float4*)&Wl[k * 128 + tc * 4];
#pragma unroll
        for (int r = 0; r < 4; ++r) {
            float xv = Xl[(tr * 4 + r) * 128 + k];
            acc[r][0] = fmaf(xv, w.x, acc[r][0]);
            acc[r][1] = fmaf(xv, w.y, acc[r][1]);
            acc[r][2] = fmaf(xv, w.z, acc[r][2]);
            acc[r][3] = fmaf(xv, w.w, acc[r][3]);
        }
    }
#pragma unroll
    for (int r = 0; r < 4; ++r) {
        int row = row0 + tr * 4 + r;
        float s = dinv[row];
        float4 v = make_float4(acc[r][0] * s, acc[r][1] * s, acc[r][2] * s, acc[r][3] * s);
        ((float4*)(hs + (long long)row * 128))[tc] = v;
    }
}

// ---------------- aggregate layer 1: h = relu(dinv*(hs[n] + sum hs[nbr]) + b1) ----------------
__global__ __launch_bounds__(256) void k_agg1(const float* __restrict__ hs, const int* __restrict__ rowptr,
                                              const int* __restrict__ csr, const float* __restrict__ dinv,
                                              const float* __restrict__ b1, float* __restrict__ h) {
    int n = (blockIdx.x * 256 + threadIdx.x) >> 6;
    int lane = threadIdx.x & 63;
    if (n >= N_NODES) return;
    float2 acc = ((const float2*)(hs + (long long)n * 128))[lane];  // self-loop seed
    int k = rowptr[n], end = rowptr[n + 1];
    for (; k + 3 < end; k += 4) {
        int s0 = csr[k], s1 = csr[k + 1], s2 = csr[k + 2], s3 = csr[k + 3];
        float2 a = ((const float2*)(hs + (long long)s0 * 128))[lane];
        float2 b = ((const float2*)(hs + (long long)s1 * 128))[lane];
        float2 c = ((const float2*)(hs + (long long)s2 * 128))[lane];
        float2 d = ((const float2*)(hs + (long long)s3 * 128))[lane];
        acc.x += (a.x + b.x) + (c.x + d.x);
        acc.y += (a.y + b.y) + (c.y + d.y);
    }
    for (; k < end; ++k) {
        float2 a = ((const float2*)(hs + (long long)csr[k] * 128))[lane];
        acc.x += a.x;
        acc.y += a.y;
    }
    float dv = dinv[n];
    float2 bb = ((const float2*)b1)[lane];
    float2 o;
    o.x = fmaxf(fmaf(dv, acc.x, bb.x), 0.f);
    o.y = fmaxf(fmaf(dv, acc.y, bb.y), 0.f);
    ((float2*)(h + (long long)n * 128))[lane] = o;
}

// ---------------- GEMM2: gs = (h @ W2) * dinv[row] ----------------
__global__ __launch_bounds__(256) void k_gemm2(const float* __restrict__ h, const float* __restrict__ W2,
                                               const float* __restrict__ dinv, float* __restrict__ gs) {
    __shared__ float Wl[128 * 64];
    __shared__ float Hl[32 * 132];
    int t = threadIdx.x;
    int row0 = blockIdx.x * 32;
    {
        const float4* W4 = (const float4*)W2;
        float4* Wl4 = (float4*)Wl;
#pragma unroll
        for (int i = 0; i < 8; ++i) Wl4[t + i * 256] = W4[t + i * 256];
    }
#pragma unroll
    for (int i = t; i < 1024; i += 256) {
        int r = i >> 5, c4 = i & 31;
        float4 a = ((const float4*)(h + (long long)(row0 + r) * 128))[c4];
        *(float4*)&Hl[r * 132 + c4 * 4] = a;
    }
    __syncthreads();
    int tc = t & 15;
    int tr = t >> 4;
    float acc[2][4] = {};
    for (int c = 0; c < 128; ++c) {
        float4 w = *(const float4*)&Wl[c * 64 + tc * 4];
#pragma unroll
        for (int r = 0; r < 2; ++r) {
            float hv = Hl[(tr * 2 + r) * 132 + c];
            acc[r][0] = fmaf(hv, w.x, acc[r][0]);
            acc[r][1] = fmaf(hv, w.y, acc[r][1]);
            acc[r][2] = fmaf(hv, w.z, acc[r][2]);
            acc[r][3] = fmaf(hv, w.w, acc[r][3]);
        }
    }
#pragma unroll
    for (int r = 0; r < 2; ++r) {
        int row = row0 + tr * 2 + r;
        float s = dinv[row];
        float4 v = make_float4(acc[r][0] * s, acc[r][1] * s, acc[r][2] * s, acc[r][3] * s);
        ((float4*)(gs + (long long)row * 64))[tc] = v;
    }
}

// ---------------- aggregate layer 2: out = dinv*(gs[n] + sum gs[nbr]) + b2 ----------------
__global__ __launch_bounds__(256) void k_agg2(const float* __restrict__ gs, const int* __restrict__ rowptr,
                                              const int* __restrict__ csr, const float* __restrict__ dinv,
                                              const float* __restrict__ b2, float* __restrict__ out) {
    int n = (blockIdx.x * 256 + threadIdx.x) >> 6;
    int lane = threadIdx.x & 63;
    if (n >= N_NODES) return;
    float acc = gs[(long long)n * 64 + lane];  // self-loop seed
    int k = rowptr[n], end = rowptr[n + 1];
    for (; k + 3 < end; k += 4) {
        int s0 = csr[k], s1 = csr[k + 1], s2 = csr[k + 2], s3 = csr[k + 3];
        float a = gs[(long long)s0 * 64 + lane];
        float b = gs[(long long)s1 * 64 + lane];
        float c = gs[(long long)s2 * 64 + lane];
        float d = gs[(long long)s3 * 64 + lane];
        acc += (a + b) + (c + d);
    }
    for (; k < end; ++k) acc += gs[(long long)csr[k] * 64 + lane];
    out[(long long)n * 64 + lane] = fmaf(dinv[n], acc, b2[lane]);
}

extern "C" void kernel_launch(void* const* d_in, const int* in_sizes, int n_in,
                              void* d_out, int out_size, void* d_ws, size_t ws_size,
                              hipStream_t stream) {
    const float* x  = (const float*)d_in[0];
    const float* W1 = (const float*)d_in[1];
    const float* b1 = (const float*)d_in[2];
    const float* W2 = (const float*)d_in[3];
    const float* b2 = (const float*)d_in[4];
    const int*   ei = (const int*)d_in[5];
    const int* src = ei;
    const int* dst = ei + N_EDGES;
    float* out = (float*)d_out;

    char* ws = (char*)d_ws;
    int*   csr    = (int*)(ws + 0);             // 6.4 MB
    int*   indeg  = (int*)(ws + 6400000);       // 400 KB
    int*   rowptr = (int*)(ws + 6800000);       // 400 KB + 4
    float* dinv   = (float*)(ws + 7200256);     // 400 KB
    int*   bcnt   = (int*)(ws + 7600256);       // 4 KB
    int*   bbase  = (int*)(ws + 7604352);       // 4 KB
    int*   bcur   = (int*)(ws + 7608448);       // 4 KB
    int*   bsums  = (int*)(ws + 7612544);       // tiny
    int2*  ebuf   = (int2*)(ws + 8388608);      // 12.8 MB (aliases hs; dead before gemm1)
    float* hs     = (float*)(ws + 8388608);     // 51.2 MB (also gs later)
    float* h      = (float*)(ws + 59588608);    // 51.2 MB
    float* gs     = hs;                          // hs dead after k_agg1

    k_zero<<<(N_NODES + 255) / 256, 256, 0, stream>>>(indeg, bcnt);
    k_bhist<<<(N_EDGES + 2047) / 2048, 256, 0, stream>>>(dst, indeg, bcnt);
    k_dinv<<<(N_NODES + 255) / 256, 256, 0, stream>>>(indeg, dinv);
    k_scan1<<<SCAN_BLOCKS, 256, 0, stream>>>(indeg, rowptr, bsums);
    k_scan2<<<1, 128, 0, stream>>>(bsums);
    k_scan3<<<(N_NODES + 255) / 256, 256, 0, stream>>>(rowptr, bsums);
    k_bscan<<<1, 1024, 0, stream>>>(bcnt, bbase, bcur);
    k_bscatter<<<(N_EDGES + 255) / 256, 256, 0, stream>>>(src, dst, bcur, ebuf);
    k_bfill<<<NB, 256, 0, stream>>>(ebuf, bbase, bcnt, rowptr, csr);

    k_gemm1<<<N_NODES / 32, 256, 0, stream>>>(x, W1, dinv, hs);
    k_agg1<<<(N_NODES * 64) / 256, 256, 0, stream>>>(hs, rowptr, csr, dinv, b1, h);
    k_gemm2<<<N_NODES / 32, 256, 0, stream>>>(h, W2, dinv, gs);
    k_agg2<<<(N_NODES * 64) / 256, 256, 0, stream>>>(gs, rowptr, csr, dinv, b2, out);
}

// Round 4
// 482.436 us; speedup vs baseline: 1.7468x; 1.7468x over previous
//
#include <hip/hip_runtime.h>

#define N_NODES 100000
#define N_EDGES 1600000
// DIN=128, DH=128, DOUT=64
#define BUCKET_SHIFT 9
#define NB 196                 // ceil(100000/512) super-buckets of 512 nodes
#define BIN_BLOCKS 782         // ceil(1600000/2048)

// ---------------- zero ----------------
__global__ __launch_bounds__(256) void k_zero(int* __restrict__ indeg) {
    int i = blockIdx.x * 256 + threadIdx.x;
    if (i < N_NODES) indeg[i] = 0;
}

// ---------------- indeg histogram (int4-vectorized edge loads) ----------------
__global__ __launch_bounds__(256) void k_count(const int* __restrict__ dst, int* __restrict__ indeg) {
    int i = blockIdx.x * 256 + threadIdx.x;   // over N_EDGES/4 int4s
    if (i < N_EDGES / 4) {
        int4 d = ((const int4*)dst)[i];
        atomicAdd(&indeg[d.x], 1);
        atomicAdd(&indeg[d.y], 1);
        atomicAdd(&indeg[d.z], 1);
        atomicAdd(&indeg[d.w], 1);
    }
}

__global__ __launch_bounds__(256) void k_dinv(const int* __restrict__ indeg, float* __restrict__ dinv) {
    int i = blockIdx.x * 256 + threadIdx.x;
    if (i < N_NODES) dinv[i] = rsqrtf(1.0f + (float)indeg[i]);  // +1 = self loop
}

// ---------------- scan pass 1: 512-node tiles (tile sums == bucket counts) ----------------
__global__ __launch_bounds__(256) void k_scan1(const int* __restrict__ indeg, int* __restrict__ rowptr,
                                               int* __restrict__ bsums) {
    __shared__ int sh[256];
    int t = threadIdx.x;
    int base = blockIdx.x * 512 + t * 2;
    int v0 = (base + 0 < N_NODES) ? indeg[base + 0] : 0;
    int v1 = (base + 1 < N_NODES) ? indeg[base + 1] : 0;
    int s = v0 + v1;
    sh[t] = s;
    __syncthreads();
    for (int off = 1; off < 256; off <<= 1) {
        int u = (t >= off) ? sh[t - off] : 0;
        __syncthreads();
        sh[t] += u;
        __syncthreads();
    }
    int excl = sh[t] - s;
    if (t == 255) bsums[blockIdx.x] = sh[t];
    if (base + 0 < N_NODES) rowptr[base + 0] = excl;
    if (base + 1 < N_NODES) rowptr[base + 1] = excl + v0;
}

// ---------------- scan pass 2: exclusive scan of NB bucket counts; init bcur ----------------
__global__ __launch_bounds__(256) void k_scan2(int* __restrict__ bsums, int* __restrict__ bcur) {
    __shared__ int sh[256];
    int t = threadIdx.x;
    int v = (t < NB) ? bsums[t] : 0;
    sh[t] = v;
    __syncthreads();
    for (int off = 1; off < 256; off <<= 1) {
        int u = (t >= off) ? sh[t - off] : 0;
        __syncthreads();
        sh[t] += u;
        __syncthreads();
    }
    if (t < NB) {
        int excl = sh[t] - v;
        bsums[t] = excl;
        bcur[t] = excl;
    }
    if (t == NB - 1) bsums[NB] = sh[t];   // == N_EDGES
}

// ---------------- scan pass 3: add bucket base to rowptr ----------------
__global__ __launch_bounds__(256) void k_scan3(int* __restrict__ rowptr, const int* __restrict__ bsums) {
    int i = blockIdx.x * 256 + threadIdx.x;
    if (i < N_NODES) rowptr[i] += bsums[i >> BUCKET_SHIFT];
    if (i == 0) rowptr[N_NODES] = N_EDGES;
}

// ---------------- bin edges into bucket-ordered packed ebuf ----------------
// block = 2048 edges in registers; LDS hist -> one global atomic per (block,bucket) -> ranked write
__global__ __launch_bounds__(256) void k_bin(const int* __restrict__ src, const int* __restrict__ dst,
                                             int* __restrict__ bcur, int* __restrict__ ebuf) {
    __shared__ int hist[NB];
    __shared__ int lbase[NB];
    int t = threadIdx.x;
    int e0 = blockIdx.x * 2048 + t;
    int s[8], d[8];
#pragma unroll
    for (int j = 0; j < 8; ++j) {
        int e = e0 + j * 256;
        bool ok = e < N_EDGES;
        s[j] = ok ? src[e] : -1;
        d[j] = ok ? dst[e] : 0;
    }
    if (t < NB) hist[t] = 0;
    __syncthreads();
#pragma unroll
    for (int j = 0; j < 8; ++j)
        if (s[j] >= 0) atomicAdd(&hist[d[j] >> BUCKET_SHIFT], 1);
    __syncthreads();
    if (t < NB && hist[t] > 0) lbase[t] = atomicAdd(&bcur[t], hist[t]);
    __syncthreads();
    if (t < NB) hist[t] = 0;
    __syncthreads();
#pragma unroll
    for (int j = 0; j < 8; ++j) {
        if (s[j] >= 0) {
            int b = d[j] >> BUCKET_SHIFT;
            int r = atomicAdd(&hist[b], 1);
            ebuf[lbase[b] + r] = ((d[j] & 511) << 17) | s[j];
        }
    }
}

// ---------------- per-bucket CSR fill: LDS cursors, writes confined to ~33KB span ----------------
__global__ __launch_bounds__(256) void k_bfill2(const int* __restrict__ ebuf, const int* __restrict__ bsums,
                                                const int* __restrict__ rowptr, int* __restrict__ csr) {
    __shared__ int cur[512];
    int b = blockIdx.x;
    int node0 = b << BUCKET_SHIFT;
    int t = threadIdx.x;
#pragma unroll
    for (int i = t; i < 512; i += 256) {
        int n = node0 + i;
        cur[i] = (n < N_NODES) ? rowptr[n] : 0;
    }
    __syncthreads();
    int s0 = bsums[b], s1 = bsums[b + 1];
    for (int i = s0 + t; i < s1; i += 256) {
        int e = ebuf[i];
        int p = atomicAdd(&cur[e >> 17], 1);
        csr[p] = e & 0x1FFFF;
    }
}

// ---------------- GEMM1: hs = (x @ W1) * dinv[row] ----------------
__global__ __launch_bounds__(256) void k_gemm1(const float* __restrict__ x, const float* __restrict__ W1,
                                               const float* __restrict__ dinv, float* __restrict__ hs) {
    __shared__ float Wl[128 * 128];
    __shared__ float Xl[32 * 128];
    int t = threadIdx.x;
    int row0 = blockIdx.x * 32;
    {
        const float4* W4 = (const float4*)W1;
        float4* Wl4 = (float4*)Wl;
#pragma unroll
        for (int i = 0; i < 16; ++i) Wl4[t + i * 256] = W4[t + i * 256];
        const float4* x4 = (const float4*)(x + (long long)row0 * 128);
        float4* Xl4 = (float4*)Xl;
#pragma unroll
        for (int i = 0; i < 4; ++i) Xl4[t + i * 256] = x4[t + i * 256];
    }
    __syncthreads();
    int tc = t & 31;
    int tr = t >> 5;
    float acc[4][4] = {};
    for (int k = 0; k < 128; ++k) {
        float4 w = *(const float4*)&Wl[k * 128 + tc * 4];
#pragma unroll
        for (int r = 0; r < 4; ++r) {
            float xv = Xl[(tr * 4 + r) * 128 + k];
            acc[r][0] = fmaf(xv, w.x, acc[r][0]);
            acc[r][1] = fmaf(xv, w.y, acc[r][1]);
            acc[r][2] = fmaf(xv, w.z, acc[r][2]);
            acc[r][3] = fmaf(xv, w.w, acc[r][3]);
        }
    }
#pragma unroll
    for (int r = 0; r < 4; ++r) {
        int row = row0 + tr * 4 + r;
        float s = dinv[row];
        float4 v = make_float4(acc[r][0] * s, acc[r][1] * s, acc[r][2] * s, acc[r][3] * s);
        ((float4*)(hs + (long long)row * 128))[tc] = v;
    }
}

// ---------------- aggregate layer 1: h = relu(dinv*(hs[n] + sum hs[nbr]) + b1) ----------------
__global__ __launch_bounds__(256) void k_agg1(const float* __restrict__ hs, const int* __restrict__ rowptr,
                                              const int* __restrict__ csr, const float* __restrict__ dinv,
                                              const float* __restrict__ b1, float* __restrict__ h) {
    int n = (blockIdx.x * 256 + threadIdx.x) >> 6;
    int lane = threadIdx.x & 63;
    if (n >= N_NODES) return;
    float2 acc = ((const float2*)(hs + (long long)n * 128))[lane];  // self-loop seed
    int k = rowptr[n], end = rowptr[n + 1];
    for (; k + 3 < end; k += 4) {
        int s0 = csr[k], s1 = csr[k + 1], s2 = csr[k + 2], s3 = csr[k + 3];
        float2 a = ((const float2*)(hs + (long long)s0 * 128))[lane];
        float2 b = ((const float2*)(hs + (long long)s1 * 128))[lane];
        float2 c = ((const float2*)(hs + (long long)s2 * 128))[lane];
        float2 d = ((const float2*)(hs + (long long)s3 * 128))[lane];
        acc.x += (a.x + b.x) + (c.x + d.x);
        acc.y += (a.y + b.y) + (c.y + d.y);
    }
    for (; k < end; ++k) {
        float2 a = ((const float2*)(hs + (long long)csr[k] * 128))[lane];
        acc.x += a.x;
        acc.y += a.y;
    }
    float dv = dinv[n];
    float2 bb = ((const float2*)b1)[lane];
    float2 o;
    o.x = fmaxf(fmaf(dv, acc.x, bb.x), 0.f);
    o.y = fmaxf(fmaf(dv, acc.y, bb.y), 0.f);
    ((float2*)(h + (long long)n * 128))[lane] = o;
}

// ---------------- GEMM2: gs = (h @ W2) * dinv[row] ----------------
__global__ __launch_bounds__(256) void k_gemm2(const float* __restrict__ h, const float* __restrict__ W2,
                                               const float* __restrict__ dinv, float* __restrict__ gs) {
    __shared__ float Wl[128 * 64];
    __shared__ float Hl[32 * 132];
    int t = threadIdx.x;
    int row0 = blockIdx.x * 32;
    {
        const float4* W4 = (const float4*)W2;
        float4* Wl4 = (float4*)Wl;
#pragma unroll
        for (int i = 0; i < 8; ++i) Wl4[t + i * 256] = W4[t + i * 256];
    }
#pragma unroll
    for (int i = t; i < 1024; i += 256) {
        int r = i >> 5, c4 = i & 31;
        float4 a = ((const float4*)(h + (long long)(row0 + r) * 128))[c4];
        *(float4*)&Hl[r * 132 + c4 * 4] = a;
    }
    __syncthreads();
    int tc = t & 15;
    int tr = t >> 4;
    float acc[2][4] = {};
    for (int c = 0; c < 128; ++c) {
        float4 w = *(const float4*)&Wl[c * 64 + tc * 4];
#pragma unroll
        for (int r = 0; r < 2; ++r) {
            float hv = Hl[(tr * 2 + r) * 132 + c];
            acc[r][0] = fmaf(hv, w.x, acc[r][0]);
            acc[r][1] = fmaf(hv, w.y, acc[r][1]);
            acc[r][2] = fmaf(hv, w.z, acc[r][2]);
            acc[r][3] = fmaf(hv, w.w, acc[r][3]);
        }
    }
#pragma unroll
    for (int r = 0; r < 2; ++r) {
        int row = row0 + tr * 2 + r;
        float s = dinv[row];
        float4 v = make_float4(acc[r][0] * s, acc[r][1] * s, acc[r][2] * s, acc[r][3] * s);
        ((float4*)(gs + (long long)row * 64))[tc] = v;
    }
}

// ---------------- aggregate layer 2: out = dinv*(gs[n] + sum gs[nbr]) + b2 ----------------
__global__ __launch_bounds__(256) void k_agg2(const float* __restrict__ gs, const int* __restrict__ rowptr,
                                              const int* __restrict__ csr, const float* __restrict__ dinv,
                                              const float* __restrict__ b2, float* __restrict__ out) {
    int n = (blockIdx.x * 256 + threadIdx.x) >> 6;
    int lane = threadIdx.x & 63;
    if (n >= N_NODES) return;
    float acc = gs[(long long)n * 64 + lane];  // self-loop seed
    int k = rowptr[n], end = rowptr[n + 1];
    for (; k + 3 < end; k += 4) {
        int s0 = csr[k], s1 = csr[k + 1], s2 = csr[k + 2], s3 = csr[k + 3];
        float a = gs[(long long)s0 * 64 + lane];
        float b = gs[(long long)s1 * 64 + lane];
        float c = gs[(long long)s2 * 64 + lane];
        float d = gs[(long long)s3 * 64 + lane];
        acc += (a + b) + (c + d);
    }
    for (; k < end; ++k) acc += gs[(long long)csr[k] * 64 + lane];
    out[(long long)n * 64 + lane] = fmaf(dinv[n], acc, b2[lane]);
}

extern "C" void kernel_launch(void* const* d_in, const int* in_sizes, int n_in,
                              void* d_out, int out_size, void* d_ws, size_t ws_size,
                              hipStream_t stream) {
    const float* x  = (const float*)d_in[0];
    const float* W1 = (const float*)d_in[1];
    const float* b1 = (const float*)d_in[2];
    const float* W2 = (const float*)d_in[3];
    const float* b2 = (const float*)d_in[4];
    const int*   ei = (const int*)d_in[5];
    const int* src = ei;
    const int* dst = ei + N_EDGES;
    float* out = (float*)d_out;

    char* ws = (char*)d_ws;
    int*   csr    = (int*)(ws + 0);             // 6.4 MB
    int*   indeg  = (int*)(ws + 6400000);       // 400 KB
    int*   rowptr = (int*)(ws + 6800000);       // 400 KB + 4
    float* dinv   = (float*)(ws + 7200256);     // 400 KB
    int*   bsums  = (int*)(ws + 7600256);       // (NB+1) ints
    int*   bcur   = (int*)(ws + 7604352);       // NB ints
    int*   ebuf   = (int*)(ws + 8388608);       // 6.4 MB packed (aliases hs; dead before gemm1)
    float* hs     = (float*)(ws + 8388608);     // 51.2 MB (also gs later)
    float* h      = (float*)(ws + 59588608);    // 51.2 MB
    float* gs     = hs;                          // hs dead after k_agg1

    k_zero<<<(N_NODES + 255) / 256, 256, 0, stream>>>(indeg);
    k_count<<<(N_EDGES / 4 + 255) / 256, 256, 0, stream>>>(dst, indeg);
    k_dinv<<<(N_NODES + 255) / 256, 256, 0, stream>>>(indeg, dinv);
    k_scan1<<<NB, 256, 0, stream>>>(indeg, rowptr, bsums);
    k_scan2<<<1, 256, 0, stream>>>(bsums, bcur);
    k_scan3<<<(N_NODES + 255) / 256, 256, 0, stream>>>(rowptr, bsums);
    k_bin<<<BIN_BLOCKS, 256, 0, stream>>>(src, dst, bcur, ebuf);
    k_bfill2<<<NB, 256, 0, stream>>>(ebuf, bsums, rowptr, csr);

    k_gemm1<<<N_NODES / 32, 256, 0, stream>>>(x, W1, dinv, hs);
    k_agg1<<<(N_NODES * 64) / 256, 256, 0, stream>>>(hs, rowptr, csr, dinv, b1, h);
    k_gemm2<<<N_NODES / 32, 256, 0, stream>>>(h, W2, dinv, gs);
    k_agg2<<<(N_NODES * 64) / 256, 256, 0, stream>>>(gs, rowptr, csr, dinv, b2, out);
}

// Round 5
// 442.711 us; speedup vs baseline: 1.9035x; 1.0897x over previous
//
#include <hip/hip_runtime.h>

#define N_NODES 100000
#define N_EDGES 1600000
// DIN=128, DH=128, DOUT=64
#define BUCKET_SHIFT 9
#define NB 196                 // ceil(100000/512) super-buckets of 512 nodes
#define BIN_BLOCKS 782         // ceil(1600000/2048)

// bf16 helpers (RNE)
__device__ __forceinline__ unsigned short f2bf(float f) {
    unsigned int u = __float_as_uint(f);
    unsigned int r = (u + 0x7FFFu + ((u >> 16) & 1u)) >> 16;
    return (unsigned short)r;
}
__device__ __forceinline__ float bf2f(unsigned short b) {
    return __uint_as_float(((unsigned int)b) << 16);
}

// ---------------- zero ----------------
__global__ __launch_bounds__(256) void k_zero(int* __restrict__ indeg) {
    int i = blockIdx.x * 256 + threadIdx.x;
    if (i < N_NODES) indeg[i] = 0;
}

// ---------------- indeg histogram (int4-vectorized edge loads) ----------------
__global__ __launch_bounds__(256) void k_count(const int* __restrict__ dst, int* __restrict__ indeg) {
    int i = blockIdx.x * 256 + threadIdx.x;   // over N_EDGES/4 int4s
    if (i < N_EDGES / 4) {
        int4 d = ((const int4*)dst)[i];
        atomicAdd(&indeg[d.x], 1);
        atomicAdd(&indeg[d.y], 1);
        atomicAdd(&indeg[d.z], 1);
        atomicAdd(&indeg[d.w], 1);
    }
}

__global__ __launch_bounds__(256) void k_dinv(const int* __restrict__ indeg, float* __restrict__ dinv) {
    int i = blockIdx.x * 256 + threadIdx.x;
    if (i < N_NODES) dinv[i] = rsqrtf(1.0f + (float)indeg[i]);  // +1 = self loop
}

// ---------------- scan pass 1: 512-node tiles (tile sums == bucket counts) ----------------
__global__ __launch_bounds__(256) void k_scan1(const int* __restrict__ indeg, int* __restrict__ rowptr,
                                               int* __restrict__ bsums) {
    __shared__ int sh[256];
    int t = threadIdx.x;
    int base = blockIdx.x * 512 + t * 2;
    int v0 = (base + 0 < N_NODES) ? indeg[base + 0] : 0;
    int v1 = (base + 1 < N_NODES) ? indeg[base + 1] : 0;
    int s = v0 + v1;
    sh[t] = s;
    __syncthreads();
    for (int off = 1; off < 256; off <<= 1) {
        int u = (t >= off) ? sh[t - off] : 0;
        __syncthreads();
        sh[t] += u;
        __syncthreads();
    }
    int excl = sh[t] - s;
    if (t == 255) bsums[blockIdx.x] = sh[t];
    if (base + 0 < N_NODES) rowptr[base + 0] = excl;
    if (base + 1 < N_NODES) rowptr[base + 1] = excl + v0;
}

// ---------------- scan pass 2: exclusive scan of NB bucket counts; init bcur ----------------
__global__ __launch_bounds__(256) void k_scan2(int* __restrict__ bsums, int* __restrict__ bcur) {
    __shared__ int sh[256];
    int t = threadIdx.x;
    int v = (t < NB) ? bsums[t] : 0;
    sh[t] = v;
    __syncthreads();
    for (int off = 1; off < 256; off <<= 1) {
        int u = (t >= off) ? sh[t - off] : 0;
        __syncthreads();
        sh[t] += u;
        __syncthreads();
    }
    if (t < NB) {
        int excl = sh[t] - v;
        bsums[t] = excl;
        bcur[t] = excl;
    }
    if (t == NB - 1) bsums[NB] = sh[t];   // == N_EDGES
}

// ---------------- scan pass 3: add bucket base to rowptr ----------------
__global__ __launch_bounds__(256) void k_scan3(int* __restrict__ rowptr, const int* __restrict__ bsums) {
    int i = blockIdx.x * 256 + threadIdx.x;
    if (i < N_NODES) rowptr[i] += bsums[i >> BUCKET_SHIFT];
    if (i == 0) rowptr[N_NODES] = N_EDGES;
}

// ---------------- bin edges into bucket-ordered packed ebuf ----------------
__global__ __launch_bounds__(256) void k_bin(const int* __restrict__ src, const int* __restrict__ dst,
                                             int* __restrict__ bcur, int* __restrict__ ebuf) {
    __shared__ int hist[NB];
    __shared__ int lbase[NB];
    int t = threadIdx.x;
    int e0 = blockIdx.x * 2048 + t;
    int s[8], d[8];
#pragma unroll
    for (int j = 0; j < 8; ++j) {
        int e = e0 + j * 256;
        bool ok = e < N_EDGES;
        s[j] = ok ? src[e] : -1;
        d[j] = ok ? dst[e] : 0;
    }
    if (t < NB) hist[t] = 0;
    __syncthreads();
#pragma unroll
    for (int j = 0; j < 8; ++j)
        if (s[j] >= 0) atomicAdd(&hist[d[j] >> BUCKET_SHIFT], 1);
    __syncthreads();
    if (t < NB && hist[t] > 0) lbase[t] = atomicAdd(&bcur[t], hist[t]);
    __syncthreads();
    if (t < NB) hist[t] = 0;
    __syncthreads();
#pragma unroll
    for (int j = 0; j < 8; ++j) {
        if (s[j] >= 0) {
            int b = d[j] >> BUCKET_SHIFT;
            int r = atomicAdd(&hist[b], 1);
            ebuf[lbase[b] + r] = ((d[j] & 511) << 17) | s[j];
        }
    }
}

// ---------------- per-bucket CSR fill ----------------
__global__ __launch_bounds__(256) void k_bfill2(const int* __restrict__ ebuf, const int* __restrict__ bsums,
                                                const int* __restrict__ rowptr, int* __restrict__ csr) {
    __shared__ int cur[512];
    int b = blockIdx.x;
    int node0 = b << BUCKET_SHIFT;
    int t = threadIdx.x;
#pragma unroll
    for (int i = t; i < 512; i += 256) {
        int n = node0 + i;
        cur[i] = (n < N_NODES) ? rowptr[n] : 0;
    }
    __syncthreads();
    int s0 = bsums[b], s1 = bsums[b + 1];
    for (int i = s0 + t; i < s1; i += 256) {
        int e = ebuf[i];
        int p = atomicAdd(&cur[e >> 17], 1);
        csr[p] = e & 0x1FFFF;
    }
}

// ---------------- GEMM1: hsb = bf16((x @ W1) * dinv[row]) ----------------
__global__ __launch_bounds__(256) void k_gemm1(const float* __restrict__ x, const float* __restrict__ W1,
                                               const float* __restrict__ dinv, unsigned short* __restrict__ hsb) {
    __shared__ float Wl[128 * 128];
    __shared__ float Xl[32 * 128];
    int t = threadIdx.x;
    int row0 = blockIdx.x * 32;
    {
        const float4* W4 = (const float4*)W1;
        float4* Wl4 = (float4*)Wl;
#pragma unroll
        for (int i = 0; i < 16; ++i) Wl4[t + i * 256] = W4[t + i * 256];
        const float4* x4 = (const float4*)(x + (long long)row0 * 128);
        float4* Xl4 = (float4*)Xl;
#pragma unroll
        for (int i = 0; i < 4; ++i) Xl4[t + i * 256] = x4[t + i * 256];
    }
    __syncthreads();
    int tc = t & 31;
    int tr = t >> 5;
    float acc[4][4] = {};
    for (int k = 0; k < 128; ++k) {
        float4 w = *(const float4*)&Wl[k * 128 + tc * 4];
#pragma unroll
        for (int r = 0; r < 4; ++r) {
            float xv = Xl[(tr * 4 + r) * 128 + k];
            acc[r][0] = fmaf(xv, w.x, acc[r][0]);
            acc[r][1] = fmaf(xv, w.y, acc[r][1]);
            acc[r][2] = fmaf(xv, w.z, acc[r][2]);
            acc[r][3] = fmaf(xv, w.w, acc[r][3]);
        }
    }
#pragma unroll
    for (int r = 0; r < 4; ++r) {
        int row = row0 + tr * 4 + r;
        float s = dinv[row];
        ushort4 o;
        o.x = f2bf(acc[r][0] * s);
        o.y = f2bf(acc[r][1] * s);
        o.z = f2bf(acc[r][2] * s);
        o.w = f2bf(acc[r][3] * s);
        ((ushort4*)(hsb + (long long)row * 128))[tc] = o;
    }
}

// ---------------- aggregate layer 1 (bf16 gather, fp32 accum) ----------------
__global__ __launch_bounds__(256) void k_agg1(const unsigned short* __restrict__ hsb, const int* __restrict__ rowptr,
                                              const int* __restrict__ csr, const float* __restrict__ dinv,
                                              const float* __restrict__ b1, float* __restrict__ h) {
    int n = (blockIdx.x * 256 + threadIdx.x) >> 6;
    int lane = threadIdx.x & 63;
    if (n >= N_NODES) return;
    ushort2 sv = ((const ushort2*)(hsb + (long long)n * 128))[lane];  // self-loop seed
    float ax = bf2f(sv.x), ay = bf2f(sv.y);
    int k = rowptr[n], end = rowptr[n + 1];
    for (; k + 3 < end; k += 4) {
        int s0 = csr[k], s1 = csr[k + 1], s2 = csr[k + 2], s3 = csr[k + 3];
        ushort2 a = ((const ushort2*)(hsb + (long long)s0 * 128))[lane];
        ushort2 b = ((const ushort2*)(hsb + (long long)s1 * 128))[lane];
        ushort2 c = ((const ushort2*)(hsb + (long long)s2 * 128))[lane];
        ushort2 d = ((const ushort2*)(hsb + (long long)s3 * 128))[lane];
        ax += (bf2f(a.x) + bf2f(b.x)) + (bf2f(c.x) + bf2f(d.x));
        ay += (bf2f(a.y) + bf2f(b.y)) + (bf2f(c.y) + bf2f(d.y));
    }
    for (; k < end; ++k) {
        ushort2 a = ((const ushort2*)(hsb + (long long)csr[k] * 128))[lane];
        ax += bf2f(a.x);
        ay += bf2f(a.y);
    }
    float dv = dinv[n];
    float2 bb = ((const float2*)b1)[lane];
    float2 o;
    o.x = fmaxf(fmaf(dv, ax, bb.x), 0.f);
    o.y = fmaxf(fmaf(dv, ay, bb.y), 0.f);
    ((float2*)(h + (long long)n * 128))[lane] = o;
}

// ---------------- GEMM2: gsb = bf16((h @ W2) * dinv[row]) ----------------
__global__ __launch_bounds__(256) void k_gemm2(const float* __restrict__ h, const float* __restrict__ W2,
                                               const float* __restrict__ dinv, unsigned short* __restrict__ gsb) {
    __shared__ float Wl[128 * 64];
    __shared__ float Hl[32 * 132];
    int t = threadIdx.x;
    int row0 = blockIdx.x * 32;
    {
        const float4* W4 = (const float4*)W2;
        float4* Wl4 = (float4*)Wl;
#pragma unroll
        for (int i = 0; i < 8; ++i) Wl4[t + i * 256] = W4[t + i * 256];
    }
#pragma unroll
    for (int i = t; i < 1024; i += 256) {
        int r = i >> 5, c4 = i & 31;
        float4 a = ((const float4*)(h + (long long)(row0 + r) * 128))[c4];
        *(float4*)&Hl[r * 132 + c4 * 4] = a;
    }
    __syncthreads();
    int tc = t & 15;
    int tr = t >> 4;
    float acc[2][4] = {};
    for (int c = 0; c < 128; ++c) {
        float4 w = *(const float4*)&Wl[c * 64 + tc * 4];
#pragma unroll
        for (int r = 0; r < 2; ++r) {
            float hv = Hl[(tr * 2 + r) * 132 + c];
            acc[r][0] = fmaf(hv, w.x, acc[r][0]);
            acc[r][1] = fmaf(hv, w.y, acc[r][1]);
            acc[r][2] = fmaf(hv, w.z, acc[r][2]);
            acc[r][3] = fmaf(hv, w.w, acc[r][3]);
        }
    }
#pragma unroll
    for (int r = 0; r < 2; ++r) {
        int row = row0 + tr * 2 + r;
        float s = dinv[row];
        ushort4 o;
        o.x = f2bf(acc[r][0] * s);
        o.y = f2bf(acc[r][1] * s);
        o.z = f2bf(acc[r][2] * s);
        o.w = f2bf(acc[r][3] * s);
        ((ushort4*)(gsb + (long long)row * 64))[tc] = o;
    }
}

// ---------------- aggregate layer 2 (bf16 gather, fp32 accum) ----------------
__global__ __launch_bounds__(256) void k_agg2(const unsigned short* __restrict__ gsb, const int* __restrict__ rowptr,
                                              const int* __restrict__ csr, const float* __restrict__ dinv,
                                              const float* __restrict__ b2, float* __restrict__ out) {
    int n = (blockIdx.x * 256 + threadIdx.x) >> 6;
    int lane = threadIdx.x & 63;
    if (n >= N_NODES) return;
    float acc = bf2f(gsb[(long long)n * 64 + lane]);  // self-loop seed
    int k = rowptr[n], end = rowptr[n + 1];
    for (; k + 3 < end; k += 4) {
        int s0 = csr[k], s1 = csr[k + 1], s2 = csr[k + 2], s3 = csr[k + 3];
        float a = bf2f(gsb[(long long)s0 * 64 + lane]);
        float b = bf2f(gsb[(long long)s1 * 64 + lane]);
        float c = bf2f(gsb[(long long)s2 * 64 + lane]);
        float d = bf2f(gsb[(long long)s3 * 64 + lane]);
        acc += (a + b) + (c + d);
    }
    for (; k < end; ++k) acc += bf2f(gsb[(long long)csr[k] * 64 + lane]);
    out[(long long)n * 64 + lane] = fmaf(dinv[n], acc, b2[lane]);
}

extern "C" void kernel_launch(void* const* d_in, const int* in_sizes, int n_in,
                              void* d_out, int out_size, void* d_ws, size_t ws_size,
                              hipStream_t stream) {
    const float* x  = (const float*)d_in[0];
    const float* W1 = (const float*)d_in[1];
    const float* b1 = (const float*)d_in[2];
    const float* W2 = (const float*)d_in[3];
    const float* b2 = (const float*)d_in[4];
    const int*   ei = (const int*)d_in[5];
    const int* src = ei;
    const int* dst = ei + N_EDGES;
    float* out = (float*)d_out;

    char* ws = (char*)d_ws;
    int*   csr    = (int*)(ws + 0);             // 6.4 MB
    int*   indeg  = (int*)(ws + 6400000);       // 400 KB
    int*   rowptr = (int*)(ws + 6800000);       // 400 KB + 4
    float* dinv   = (float*)(ws + 7200256);     // 400 KB
    int*   bsums  = (int*)(ws + 7600256);       // (NB+1) ints
    int*   bcur   = (int*)(ws + 7604352);       // NB ints
    int*   ebuf   = (int*)(ws + 8388608);       // 6.4 MB packed (dead before gemm1)
    unsigned short* hsb = (unsigned short*)(ws + 8388608);   // 25.6 MB bf16 (aliases ebuf)
    float* h      = (float*)(ws + 59588608);    // 51.2 MB fp32
    unsigned short* gsb = hsb;                   // hsb dead after k_agg1; 12.8 MB bf16

    k_zero<<<(N_NODES + 255) / 256, 256, 0, stream>>>(indeg);
    k_count<<<(N_EDGES / 4 + 255) / 256, 256, 0, stream>>>(dst, indeg);
    k_dinv<<<(N_NODES + 255) / 256, 256, 0, stream>>>(indeg, dinv);
    k_scan1<<<NB, 256, 0, stream>>>(indeg, rowptr, bsums);
    k_scan2<<<1, 256, 0, stream>>>(bsums, bcur);
    k_scan3<<<(N_NODES + 255) / 256, 256, 0, stream>>>(rowptr, bsums);
    k_bin<<<BIN_BLOCKS, 256, 0, stream>>>(src, dst, bcur, ebuf);
    k_bfill2<<<NB, 256, 0, stream>>>(ebuf, bsums, rowptr, csr);

    k_gemm1<<<N_NODES / 32, 256, 0, stream>>>(x, W1, dinv, hsb);
    k_agg1<<<(N_NODES * 64) / 256, 256, 0, stream>>>(hsb, rowptr, csr, dinv, b1, h);
    k_gemm2<<<N_NODES / 32, 256, 0, stream>>>(h, W2, dinv, gsb);
    k_agg2<<<(N_NODES * 64) / 256, 256, 0, stream>>>(gsb, rowptr, csr, dinv, b2, out);
}